// Round 4
// baseline (674.350 us; speedup 1.0000x reference)
//
#include <hip/hip_runtime.h>
#include <hip/hip_bf16.h>
#include <stdint.h>

#define HIDDEN 2048
#define INTER  1408
#define NE     8
#define NTOK   4096
#define MAXT   40   // BM=256 tiles: sum ceil(c/256) <= 32+7

typedef __attribute__((ext_vector_type(8))) short short8;
typedef __attribute__((ext_vector_type(4))) float f32x4;

typedef const __attribute__((address_space(1))) unsigned char* gp1_t;
typedef __attribute__((address_space(3))) unsigned char* lp3_t;

__device__ __forceinline__ void lds_cp16(const void* g, void* l) {
    __builtin_amdgcn_global_load_lds((gp1_t)g, (lp3_t)l, 16, 0, 0);
}

__device__ __forceinline__ float bf2f(short s) {
    union { float f; unsigned u; } u; u.u = ((unsigned)(unsigned short)s) << 16; return u.f;
}

// ---------------- fp32 -> bf16 weight conversion (gate_up + down fused) --------
#define C1 (NE * 2 * INTER * HIDDEN / 4)
#define C2 (NE * HIDDEN * INTER / 4)
__global__ void cvt_w_kernel(const float* __restrict__ gu, const float* __restrict__ dn,
                             __hip_bfloat16* __restrict__ gub, __hip_bfloat16* __restrict__ dnb) {
    long c = (long)blockIdx.x * blockDim.x + threadIdx.x;
    const float* s; __hip_bfloat16* d; long o;
    if (c < C1) { s = gu; d = gub; o = c; }
    else        { s = dn; d = dnb; o = c - C1; }
    o *= 4;
    float4 v = *(const float4*)(s + o);
    *(__hip_bfloat162*)(d + o)     = __float22bfloat162_rn(make_float2(v.x, v.y));
    *(__hip_bfloat162*)(d + o + 2) = __float22bfloat162_rn(make_float2(v.z, v.w));
}

// ---------------- router ----------------
__global__ void router_kernel(const float* __restrict__ x, const float* __restrict__ rw,
                              int* __restrict__ counts, int* __restrict__ topk_e,
                              float* __restrict__ topk_w, __hip_bfloat16* __restrict__ xb) {
    int wave = threadIdx.x >> 6;
    int lane = threadIdx.x & 63;
    int t = blockIdx.x * 4 + wave;
    const float4* xr = (const float4*)(x + (size_t)t * HIDDEN);
    __hip_bfloat16* xbr = xb + (size_t)t * HIDDEN;
    float acc[NE] = {0.f,0.f,0.f,0.f,0.f,0.f,0.f,0.f};
    #pragma unroll
    for (int c = lane; c < HIDDEN / 4; c += 64) {
        float4 v = xr[c];
        *(__hip_bfloat162*)(xbr + c * 4)     = __float22bfloat162_rn(make_float2(v.x, v.y));
        *(__hip_bfloat162*)(xbr + c * 4 + 2) = __float22bfloat162_rn(make_float2(v.z, v.w));
        #pragma unroll
        for (int e = 0; e < NE; ++e) {
            float4 w = ((const float4*)(rw + e * HIDDEN))[c];
            acc[e] += v.x * w.x + v.y * w.y + v.z * w.z + v.w * w.w;
        }
    }
    #pragma unroll
    for (int e = 0; e < NE; ++e) {
        #pragma unroll
        for (int off = 32; off > 0; off >>= 1) acc[e] += __shfl_xor(acc[e], off, 64);
    }
    if (lane == 0) {
        int i1 = 0; float v1 = acc[0];
        for (int e = 1; e < NE; ++e) if (acc[e] > v1) { v1 = acc[e]; i1 = e; }
        int i2 = -1; float v2 = -3.0e38f;
        for (int e = 0; e < NE; ++e) if (e != i1 && acc[e] > v2) { v2 = acc[e]; i2 = e; }
        float w1 = 1.f / (1.f + expf(v2 - v1));
        float w2 = 1.f - w1;
        topk_e[t * 2 + 0] = i1; topk_e[t * 2 + 1] = i2;
        topk_w[t * 2 + 0] = w1; topk_w[t * 2 + 1] = w2;
        atomicAdd(&counts[i1], 1);
        atomicAdd(&counts[i2], 1);
    }
}

__global__ void scan_kernel(const int* __restrict__ counts, int* __restrict__ offsets,
                            int* __restrict__ cursor, int* __restrict__ tiles,
                            int* __restrict__ n_tiles) {
    if (threadIdx.x == 0) {
        int s = 0, nt = 0;
        for (int e = 0; e < NE; ++e) {
            offsets[e] = s; cursor[e] = s;
            int c = counts[e]; s += c;
            for (int mt = 0; mt * 256 < c; ++mt) tiles[nt++] = (e << 16) | mt;
        }
        n_tiles[0] = nt;
    }
}

__global__ void scatter_kernel(const int* __restrict__ topk_e, const float* __restrict__ topk_w,
                               int* __restrict__ cursor, int* __restrict__ slot_tid,
                               float* __restrict__ slot_w, int* __restrict__ tok2slot) {
    int k = blockIdx.x * blockDim.x + threadIdx.x;
    if (k >= NTOK * 2) return;
    int e = topk_e[k];
    int slot = atomicAdd(&cursor[e], 1);
    slot_tid[slot] = k >> 1;
    slot_w[slot]   = topk_w[k];
    tok2slot[k]    = slot;
}

// =====================================================================
// moe_gemm<WHICH>: BM=256 x BN=256(B-rows) x BK=64; 8 waves (2m x 4n);
// wave tile 128x64; 16x16x32 MFMA. LDS: 2 buf x {A,B} x {kh0,kh1}
// [256][32] regions (16 KB each, 128 KB total).
// TWO balanced phases per K-tile (one per kh): each phase =
//   12 ds_read_b128 (96 KB/CU ~ 1000cy) + 2 stage half-tiles (4 cp16)
//   + 32 MFMA (1242cy/SIMD pipe) + vmcnt(4) + barrier.
// No intra-phase lgkmcnt(0)/sched_barrier: compiler emits counted lgkm
// waits and interleaves reads with MFMAs. Stage slack >= 1.5 phases.
// =====================================================================

#define FENCE asm volatile("" ::: "memory")
#define W_V4  asm volatile("s_waitcnt vmcnt(4)" ::: "memory")
#define W_V0  asm volatile("s_waitcnt vmcnt(0)" ::: "memory")
#define BAR do { __builtin_amdgcn_sched_barrier(0); FENCE; \
                 __builtin_amdgcn_s_barrier(); FENCE; \
                 __builtin_amdgcn_sched_barrier(0); } while (0)

#define DSA(Rg, mf) (*(const short8*)((Rg) + laneA + (mf) * 512))
#define DSB(Rg, nf) (*(const short8*)((Rg) + laneB + (nf) * 512))

// One phase: kh half of K-tile T (buffer b_ = T&1).
//   DOSTAGE: prefetch kh half of tile T+1 into buffer b_^1.
//   DOWAIT: 0 = none (final phase), 4 = vmcnt(4), -1 = vmcnt(0).
#define PHASE(T, KH, DOSTAGE, DOWAIT, DOBAR) do {                            \
    const int b_ = (T) & 1;                                                  \
    const __hip_bfloat16* RA_ = smem + (((b_ << 2) | (KH)) << 13);           \
    const __hip_bfloat16* RB_ = smem + (((b_ << 2) | 2 | (KH)) << 13);       \
    short8 afr[8], bfr[4];                                                   \
    _Pragma("unroll") for (int mf_ = 0; mf_ < 8; ++mf_) afr[mf_] = DSA(RA_, mf_); \
    _Pragma("unroll") for (int nf_ = 0; nf_ < 4; ++nf_) bfr[nf_] = DSB(RB_, nf_); \
    if (DOSTAGE) { stage(0, (KH), (T) + 1, b_ ^ 1); stage(1, (KH), (T) + 1, b_ ^ 1); } \
    __builtin_amdgcn_s_setprio(1);                                           \
    _Pragma("unroll") for (int mf_ = 0; mf_ < 8; ++mf_)                      \
        _Pragma("unroll") for (int nf_ = 0; nf_ < 4; ++nf_)                  \
            acc[mf_][nf_] = __builtin_amdgcn_mfma_f32_16x16x32_bf16(         \
                afr[mf_], bfr[nf_], acc[mf_][nf_], 0, 0, 0);                 \
    __builtin_amdgcn_s_setprio(0);                                           \
    if ((DOWAIT) == 4) { W_V4; } else if ((DOWAIT) < 0) { W_V0; }            \
    if (DOBAR) { BAR; }                                                      \
} while (0)

template<int WHICH>  // 1 = gate_up+silu, 2 = down-proj
__global__ __launch_bounds__(512, 2) void moe_gemm(
    const __hip_bfloat16* __restrict__ Ag,
    const __hip_bfloat16* __restrict__ Bg,
    const int* __restrict__ counts, const int* __restrict__ offsets,
    const int* __restrict__ tiles, const int* __restrict__ n_tiles,
    const int* __restrict__ slot_tid, const float* __restrict__ slot_w,
    __hip_bfloat16* __restrict__ Out)
{
    constexpr int KDIM = (WHICH == 1) ? HIDDEN : INTER;
    constexpr int NT   = KDIM / 64;

    const int ti = blockIdx.y;
    if (ti >= n_tiles[0]) return;
    const int tile = tiles[ti];
    const int e  = tile >> 16;
    const int mt = tile & 0xffff;
    const int nt = blockIdx.x;
    const int count = counts[e];
    const int off = offsets[e];

    extern __shared__ __hip_bfloat16 smem[];

    const int tid  = threadIdx.x;
    const int wave = tid >> 6;
    const int lane = tid & 63;
    const int wm = wave >> 2, wn = wave & 3;
    const int l15 = lane & 15;
    const int q   = lane >> 4;
    const int sw  = (l15 >> 1) & 3;

    // element offsets within a [256][32] region; XOR swizzle pos = q ^ ((r>>1)&3).
    const int laneA = (wm * 128 + l15) * 32 + ((q ^ sw) << 3);
    const int laneB = (wn * 64  + l15) * 32 + ((q ^ sw) << 3);

    // staging source pointers; thread handles chunk cs = j*512+tid of each region.
    const __hip_bfloat16* PA[2];
    const __hip_bfloat16* PB[2];
    #pragma unroll
    for (int j = 0; j < 2; ++j) {
        int cs  = j * 512 + tid;
        int row = cs >> 2;
        int kc  = (cs & 3) ^ ((row >> 1) & 3);   // inverse (== same) XOR on source
        int rg  = mt * 256 + row;
        int rc  = rg < count ? rg : count - 1;
        if constexpr (WHICH == 1) {
            int tok = slot_tid[off + rc];
            PA[j] = Ag + (size_t)tok * HIDDEN + kc * 8;
            int p = row >> 5, sel = (row >> 4) & 1, idx = row & 15;
            int hc = nt * 128 + p * 16 + idx;
            int grow = sel ? (INTER + hc) : hc;
            PB[j] = Bg + ((size_t)(e * 2 * INTER + grow)) * HIDDEN + kc * 8;
        } else {
            PA[j] = Ag + (size_t)(off + rc) * INTER + kc * 8;
            PB[j] = Bg + ((size_t)(e * HIDDEN + nt * 256 + row)) * INTER + kc * 8;
        }
    }

    // stage one half-tile (m: 0=A 1=B; kh region) of K-tile kt into buffer b.
    auto stage = [&](int m, int kh, int kt, int b) {
        __hip_bfloat16* L = smem + (size_t)(((b << 2) | (m << 1) | kh) << 13);
        const __hip_bfloat16* s0 = (m ? PB[0] : PA[0]) + kt * 64 + kh * 32;
        const __hip_bfloat16* s1 = (m ? PB[1] : PA[1]) + kt * 64 + kh * 32;
        lds_cp16(s0, L + tid * 8);
        lds_cp16(s1, L + (512 + tid) * 8);
    };

    f32x4 acc[8][4];
    #pragma unroll
    for (int mf = 0; mf < 8; ++mf)
        #pragma unroll
        for (int nf = 0; nf < 4; ++nf) acc[mf][nf] = (f32x4)0.f;

    // prologue: tile 0 both halves; wait kh0 (first 4 ops), kh1 stays in flight
    stage(0, 0, 0, 0); stage(1, 0, 0, 0);
    stage(0, 1, 0, 0); stage(1, 1, 0, 0);
    W_V4; BAR;

    #pragma unroll 2
    for (int t = 0; t < NT - 1; ++t) {
        PHASE(t, 0, 1, 4, 1);
        PHASE(t, 1, 1, 4, 1);
    }
    PHASE(NT - 1, 0, 0, -1, 1);
    PHASE(NT - 1, 1, 0, 0, 0);

    // epilogue: D col = lane&15 (B extent), row = (lane>>4)*4 + reg (A extent)
    if constexpr (WHICH == 1) {
        #pragma unroll
        for (int mf = 0; mf < 8; ++mf) {
            #pragma unroll
            for (int reg = 0; reg < 4; ++reg) {
                int row = wm * 128 + mf * 16 + q * 4 + reg;
                int rg  = mt * 256 + row;
                if (rg < count) {
                    float wgt = slot_w[off + rg];
                    #pragma unroll
                    for (int g = 0; g < 2; ++g) {
                        float gv = acc[mf][2 * g + 0][reg];
                        float uv = acc[mf][2 * g + 1][reg];
                        float hv = gv / (1.f + __expf(-gv)) * uv * wgt;
                        Out[(size_t)(off + rg) * INTER + nt * 128 + (wn * 2 + g) * 16 + l15] =
                            __float2bfloat16(hv);
                    }
                }
            }
        }
    } else {
        #pragma unroll
        for (int mf = 0; mf < 8; ++mf) {
            #pragma unroll
            for (int reg = 0; reg < 4; ++reg) {
                int row = wm * 128 + mf * 16 + q * 4 + reg;
                int rg  = mt * 256 + row;
                if (rg < count) {
                    size_t base = (size_t)(off + rg) * HIDDEN + nt * 256 + wn * 64;
                    #pragma unroll
                    for (int nf = 0; nf < 4; ++nf)
                        Out[base + nf * 16 + l15] = __float2bfloat16(acc[mf][nf][reg]);
                }
            }
        }
    }
}

// ---------------- combine ----------------
__global__ void combine_kernel(const __hip_bfloat16* __restrict__ eo,
                               const int* __restrict__ tok2slot,
                               float* __restrict__ out) {
    int idx = blockIdx.x * blockDim.x + threadIdx.x;
    int t = idx >> 8;
    int c = (idx & 255) * 8;
    int s1 = tok2slot[t * 2], s2 = tok2slot[t * 2 + 1];
    short8 v1 = *(const short8*)(eo + (size_t)s1 * HIDDEN + c);
    short8 v2 = *(const short8*)(eo + (size_t)s2 * HIDDEN + c);
    float4 o0, o1;
    o0.x = bf2f(v1[0]) + bf2f(v2[0]); o0.y = bf2f(v1[1]) + bf2f(v2[1]);
    o0.z = bf2f(v1[2]) + bf2f(v2[2]); o0.w = bf2f(v1[3]) + bf2f(v2[3]);
    o1.x = bf2f(v1[4]) + bf2f(v2[4]); o1.y = bf2f(v1[5]) + bf2f(v2[5]);
    o1.z = bf2f(v1[6]) + bf2f(v2[6]); o1.w = bf2f(v1[7]) + bf2f(v2[7]);
    float* op = out + (size_t)t * HIDDEN + c;
    *(float4*)op = o0;
    *(float4*)(op + 4) = o1;
}

extern "C" void kernel_launch(void* const* d_in, const int* in_sizes, int n_in,
                              void* d_out, int out_size, void* d_ws, size_t ws_size,
                              hipStream_t stream)
{
    (void)in_sizes; (void)n_in; (void)ws_size; (void)out_size;
    const float* x  = (const float*)d_in[0];
    const float* rw = (const float*)d_in[1];
    const float* gu = (const float*)d_in[2];
    const float* dn = (const float*)d_in[3];

    char* p = (char*)d_ws;
    auto take = [&](size_t bytes) { char* r = p; p += (bytes + 255) & ~(size_t)255; return r; };
    __hip_bfloat16* xb  = (__hip_bfloat16*)take((size_t)NTOK * HIDDEN * 2);
    __hip_bfloat16* gub = (__hip_bfloat16*)take((size_t)NE * 2 * INTER * HIDDEN * 2);
    __hip_bfloat16* dnb = (__hip_bfloat16*)take((size_t)NE * HIDDEN * INTER * 2);
    __hip_bfloat16* hbuf= (__hip_bfloat16*)take((size_t)(2 * NTOK + 256) * INTER * 2);
    int*   counts   = (int*)take(64);
    int*   offsets  = (int*)take(64);
    int*   cursor   = (int*)take(64);
    int*   ntile    = (int*)take(64);
    int*   tiles    = (int*)take(MAXT * 4);
    int*   topk_e   = (int*)take((size_t)NTOK * 2 * 4);
    float* topk_w   = (float*)take((size_t)NTOK * 2 * 4);
    int*   slot_tid = (int*)take((size_t)(2 * NTOK + 256) * 4);
    float* slot_w   = (float*)take((size_t)(2 * NTOK + 256) * 4);
    int*   tok2slot = (int*)take((size_t)NTOK * 2 * 4);
    // eo aliases gub scratch: gub dead after gemm1, eo (33.5 MB) < gub (92.3 MB)
    __hip_bfloat16* eo = gub;

    hipFuncSetAttribute((const void*)moe_gemm<1>,
                        hipFuncAttributeMaxDynamicSharedMemorySize, 131072);
    hipFuncSetAttribute((const void*)moe_gemm<2>,
                        hipFuncAttributeMaxDynamicSharedMemorySize, 131072);

    hipMemsetAsync(counts, 0, 64, stream);

    cvt_w_kernel<<<dim3((C1 + C2) / 256), 256, 0, stream>>>(gu, dn, gub, dnb);

    router_kernel<<<dim3(NTOK / 4), 256, 0, stream>>>(x, rw, counts, topk_e, topk_w, xb);
    scan_kernel<<<dim3(1), 64, 0, stream>>>(counts, offsets, cursor, tiles, ntile);
    scatter_kernel<<<dim3((NTOK * 2) / 256), 256, 0, stream>>>(topk_e, topk_w, cursor,
                                                               slot_tid, slot_w, tok2slot);

    moe_gemm<1><<<dim3(INTER / 128, MAXT), 512, 131072, stream>>>(
        xb, gub, counts, offsets, tiles, ntile, slot_tid, slot_w, hbuf);
    moe_gemm<2><<<dim3(HIDDEN / 256, MAXT), 512, 131072, stream>>>(
        hbuf, dnb, counts, offsets, tiles, ntile, slot_tid, slot_w, eo);
    combine_kernel<<<dim3(NTOK * HIDDEN / 8 / 256), 256, 0, stream>>>(
        eo, tok2slot, (float*)d_out);
}